// Round 1
// 773.384 us; speedup vs baseline: 1.1400x; 1.1400x over previous
//
#include <hip/hip_runtime.h>
#include <hip/hip_bf16.h>

#define B_ 16
#define N_ 4096
#define D_ 1024
#define K_ 1024
#define M_ 3072

typedef unsigned short u16;
typedef unsigned int u32;
typedef unsigned long long u64;
typedef __attribute__((ext_vector_type(8))) short bf16x8;
typedef __attribute__((ext_vector_type(4))) float f32x4;

// round-to-nearest-even fp32 -> bf16
__device__ inline u16 bf16_rn(float x) {
    unsigned u = __float_as_uint(x);
    u += 0x7fffu + ((u >> 16) & 1u);
    return (u16)(u >> 16);
}
__device__ inline void bf16_split(float x, u16& h, u16& l) {
    h = bf16_rn(x);
    const float hf = __uint_as_float(((unsigned)h) << 16);
    l = bf16_rn(x - hf);
}

// ---------------------------------------------------------------------------
// Kernel 1: per-batch top-K via u64 radix select (unchanged).
// ---------------------------------------------------------------------------
__global__ __launch_bounds__(1024)
void topk_kernel(const float* __restrict__ scores,
                 float* __restrict__ out_idx_f, float* __restrict__ out_sc,
                 int* __restrict__ kept_idx, int* __restrict__ dropped_idx,
                 float* __restrict__ kept_sc, u32* __restrict__ rank,
                 u64* __restrict__ assign_key)
{
    const int b = blockIdx.x;
    const int tid = threadIdx.x;
    __shared__ u32 hist[2048];
    __shared__ u32 wsum[16];
    __shared__ u64 s_thr;
    __shared__ u32 s_bb;

    for (int m = tid; m < M_; m += 1024) assign_key[b * M_ + m] = 0ull;

    float sval[4];
    u64 key[4];
#pragma unroll
    for (int r = 0; r < 4; ++r) {
        const int e = r * 1024 + tid;
        const float s = scores[b * N_ + e];
        sval[r] = s;
        unsigned sb = __float_as_uint(s);
        sb = (sb & 0x80000000u) ? ~sb : (sb | 0x80000000u);
        key[r] = ((u64)sb << 32) | (unsigned)(N_ - 1 - e);
    }

    u64 prefix = 0;
    u32 need = K_;
    int consumed = 0;
    bool done = false;

#pragma unroll
    for (int lvl = 0; lvl < 6; ++lvl) {
        if (!done) {
            const int w = (lvl < 5) ? 11 : 9;
            const int sh = 64 - consumed - w;

            hist[tid] = 0u; hist[tid + 1024] = 0u;
            __syncthreads();
#pragma unroll
            for (int r = 0; r < 4; ++r) {
                const bool cand = (lvl == 0) || ((key[r] >> (64 - consumed)) == prefix);
                if (cand) atomicAdd(&hist[(u32)(key[r] >> sh) & ((1u << w) - 1u)], 1u);
            }
            __syncthreads();
            for (int d = 1; d < 2048; d <<= 1) {
                const u32 v0 = (tid + d < 2048) ? hist[tid + d] : 0u;
                const u32 v1 = (tid + 1024 + d < 2048) ? hist[tid + 1024 + d] : 0u;
                __syncthreads();
                hist[tid] += v0; hist[tid + 1024] += v1;
                __syncthreads();
            }
#pragma unroll
            for (int h = 0; h < 2; ++h) {
                const int i = tid + h * 1024;
                if (hist[i] >= need && (i == 2047 || hist[i + 1] < need)) s_bb = (u32)i;
            }
            __syncthreads();
            const u32 bb = s_bb;
            const u32 c_hi = (bb < 2047u) ? hist[bb + 1] : 0u;
            const u32 cnt_bb = hist[bb] - c_hi;
            __syncthreads();

            prefix = (prefix << w) | bb;
            consumed += w;
            need -= c_hi;
            if (cnt_bb == need || consumed == 64) {
                if (tid == 0) s_thr = prefix << (64 - consumed);
                done = true;
            }
        }
    }
    __syncthreads();
    const u64 thr = s_thr;

    const int lane = tid & 63, wv = tid >> 6;
    unsigned carry = 0;
#pragma unroll
    for (int r = 0; r < 4; ++r) {
        const int e = r * 1024 + tid;
        const bool kept = (key[r] >= thr);

        const u64 mb = __ballot(kept);
        const unsigned lanePre = (unsigned)__popcll(mb & ((1ull << lane) - 1ull));
        if (lane == 0) wsum[wv] = (unsigned)__popcll(mb);
        __syncthreads();
        unsigned waveExcl = 0, roundTot = 0;
        for (int i = 0; i < 16; ++i) {
            const unsigned v = wsum[i];
            if (i < wv) waveExcl += v;
            roundTot += v;
        }
        const unsigned kpos = carry + waveExcl + lanePre;
        if (kept) {
            out_idx_f[b * K_ + kpos] = (float)e;
            out_sc  [b * K_ + kpos] = sval[r];
            kept_idx[b * K_ + kpos] = e;
            kept_sc [b * K_ + kpos] = fmaxf(sval[r], 0.0f);
            rank    [b * N_ + e]    = kpos;
        } else {
            const unsigned q = (unsigned)e - kpos;
            dropped_idx[b * M_ + q] = e;
            rank       [b * N_ + e] = (u32)K_ + q;
        }
        carry += roundTot;
        __syncthreads();
    }
}

// ---------------------------------------------------------------------------
// Kernel 2 (fused prep+conv): unchanged.
// ---------------------------------------------------------------------------
__global__ __launch_bounds__(256)
void convert_kernel(const float* __restrict__ tokens, const u32* __restrict__ rank,
                    u16* __restrict__ khi, u16* __restrict__ klo,
                    u16* __restrict__ dhi, u16* __restrict__ dlo)
{
    const int w = threadIdx.x >> 6, lane = threadIdx.x & 63;
    const int g = blockIdx.x * 4 + w;          // flat row in [0, B*N)
    const int b = g >> 12;                     // N_ = 4096
    const float* src = tokens + (size_t)g * D_;

    float4 v[4];
    float ss = 0.0f;
#pragma unroll
    for (int j = 0; j < 4; ++j) {
        v[j] = *(const float4*)(src + (lane + j * 64) * 4);
        ss += v[j].x * v[j].x + v[j].y * v[j].y + v[j].z * v[j].z + v[j].w * v[j].w;
    }
#pragma unroll
    for (int sh = 1; sh < 64; sh <<= 1) ss += __shfl_xor(ss, sh, 64);
    const float inv = 1.0f / fmaxf(sqrtf(ss), 1e-12f);

    const u32 r = rank[g];
    u16 *hp, *lp;
    if (r < (u32)K_) {
        hp = khi + ((size_t)b * K_ + r) * D_;
        lp = klo + ((size_t)b * K_ + r) * D_;
    } else {
        hp = dhi + ((size_t)b * M_ + (r - K_)) * D_;
        lp = dlo + ((size_t)b * M_ + (r - K_)) * D_;
    }
#pragma unroll
    for (int j = 0; j < 4; ++j) {
        ushort4 h, l;
        bf16_split(v[j].x * inv, h.x, l.x);
        bf16_split(v[j].y * inv, h.y, l.y);
        bf16_split(v[j].z * inv, h.z, l.z);
        bf16_split(v[j].w * inv, h.w, l.w);
        *(ushort4*)(hp + 4 * (lane + 64 * j)) = h;
        *(ushort4*)(lp + 4 * (lane + 64 * j)) = l;
    }
}

// ---------------------------------------------------------------------------
// Kernel 3 (MFMA, 8-phase counted-vmcnt): sim = d_norm . k_norm^T.
// 3-pass split-bf16 expressed as one GEMM over K = 3 x 1024 segments:
//   seg0: dhi.khi   seg1: dlo.khi   seg2: dhi.klo
// Geometry: BM=BN=256, BK=64, 8 waves (2Mx4N), 512 thr, LDS 128 KiB.
// LDS = 8 slots x 16 KiB: {A,B} x {quadrant q0/q1} x {K-step parity P0/P1},
// fragment-ordered (wave-linear global_load_lds dest -> 0 bank conflicts).
// Per iteration: 8 phases cover K-steps 2i (ph1-4) and 2i+1 (ph5-8); each
// phase = {ds_read frags, stage one slot, [vmcnt(4) at ph4/8], s_barrier,
// setprio(1) 16xMFMA setprio(0), s_barrier}. vmcnt never drains to 0 in
// steady state (T3+T4); each slot restaged >=1 barrier after its last read:
//   ph1:Aq1P1<-t1  ph2:Bq1P1<-t1  ph3:Aq0P0<-t2  ph4:Bq0P0<-t2
//   ph5:Aq1P0<-t2  ph6:Bq1P0<-t2  ph7:Aq0P1<-t3  ph8:Bq0P1<-t3
// vmcnt(4) at ph4 leaves {ph3,ph4} in flight -> everything needed by ph5-8
// landed; at ph8 leaves {ph7,ph8} -> everything for next ph1-4 landed.
// Fused row-argmax epilogue via packed u64 atomicMax (max sim, tie -> min n).
// ---------------------------------------------------------------------------
#define BAR() asm volatile("s_barrier" ::: "memory")

#define MFMA16(FRQ, FCQ) do {                                               \
    __builtin_amdgcn_s_setprio(1);                                          \
    _Pragma("unroll") for (int i_ = 0; i_ < 4; ++i_)                        \
    _Pragma("unroll") for (int j_ = 0; j_ < 2; ++j_) {                      \
        acc[FRQ][FCQ][i_][j_] = __builtin_amdgcn_mfma_f32_16x16x32_bf16(    \
            fa[i_][0], fb[j_][0], acc[FRQ][FCQ][i_][j_], 0, 0, 0);          \
        acc[FRQ][FCQ][i_][j_] = __builtin_amdgcn_mfma_f32_16x16x32_bf16(    \
            fa[i_][1], fb[j_][1], acc[FRQ][FCQ][i_][j_], 0, 0, 0);          \
    }                                                                       \
    __builtin_amdgcn_s_setprio(0);                                          \
} while (0)

__global__ __launch_bounds__(512)
void sim_mfma_kernel(const u16* __restrict__ dhi, const u16* __restrict__ dlo,
                     const u16* __restrict__ khi, const u16* __restrict__ klo,
                     u64* __restrict__ assign_key)
{
    // XCD-aware swizzle: 768 blocks = 8 XCD x 96; within an XCD, 12
    // consecutive blocks share nt (kept panel) for L2 reuse.
    const int gid = blockIdx.x;
    const int vid = (gid & 7) * 96 + (gid >> 3);
    const int bb  = vid / 48;
    const int tt  = vid - bb * 48;
    const int nt  = tt / 12;                   // [0,4)  kept tile (256)
    const int mt  = tt - nt * 12;              // [0,12) dropped tile (256)

    const int tid = threadIdx.x;
    const int w = tid >> 6, lane = tid & 63;
    const int wr = w >> 2, wc = w & 3;         // wave grid 2(M) x 4(N)
    const int wr4 = wr * 4, wc2 = wc * 2;
    const int lrow = lane >> 4, lcol = lane & 15;

    __shared__ __align__(16) char smem[131072];
    const char* sA = smem + lane * 16;
    const char* sB = smem + 65536 + lane * 16;

    // per-lane global row offsets (wave w stages fragment-row w of a slot)
    const size_t aOff = ((size_t)bb * M_ + mt * 256 + w * 16 + lcol) * D_ + lrow * 8;
    const size_t bOff = ((size_t)bb * K_ + nt * 256 + w * 16 + lcol) * D_ + lrow * 8;

    f32x4 acc[2][2][4][2];                     // [frq][fcq][i][j]
#pragma unroll
    for (int a0 = 0; a0 < 2; ++a0)
#pragma unroll
        for (int a1 = 0; a1 < 2; ++a1)
#pragma unroll
            for (int a2 = 0; a2 < 4; ++a2)
#pragma unroll
                for (int a3 = 0; a3 < 2; ++a3)
                    acc[a0][a1][a2][a3] = (f32x4){0.f, 0.f, 0.f, 0.f};

    bf16x8 fa[4][2], fb[2][2];

    // A slot (q,P): byte off (P*2+q)*16384; B same + 65536.
    auto STAGE_A = [&](int P, int q, int t) {
        if (t < 48) {
            const u16* s = ((t >> 4) == 1) ? dlo : dhi;     // seg 0,2: hi; 1: lo
            const u16* gp = s + aOff + (size_t)(q * 131072) + ((t & 15) * 64);
            char* lp = smem + (P * 2 + q) * 16384 + w * 2048;
            __builtin_amdgcn_global_load_lds(
                (const __attribute__((address_space(1))) void*)gp,
                (__attribute__((address_space(3))) void*)lp, 16, 0, 0);
            __builtin_amdgcn_global_load_lds(
                (const __attribute__((address_space(1))) void*)(gp + 32),
                (__attribute__((address_space(3))) void*)(lp + 1024), 16, 0, 0);
        }
    };
    auto STAGE_B = [&](int P, int q, int t) {
        if (t < 48) {
            const u16* s = ((t >> 4) == 2) ? klo : khi;     // seg 0,1: hi; 2: lo
            const u16* gp = s + bOff + (size_t)(q * 131072) + ((t & 15) * 64);
            char* lp = smem + 65536 + (P * 2 + q) * 16384 + w * 2048;
            __builtin_amdgcn_global_load_lds(
                (const __attribute__((address_space(1))) void*)gp,
                (__attribute__((address_space(3))) void*)lp, 16, 0, 0);
            __builtin_amdgcn_global_load_lds(
                (const __attribute__((address_space(1))) void*)(gp + 32),
                (__attribute__((address_space(3))) void*)(lp + 1024), 16, 0, 0);
        }
    };
    auto READ_FA = [&](int qo) {
#pragma unroll
        for (int i = 0; i < 4; ++i) {
            fa[i][0] = *(const bf16x8*)(sA + qo + (wr4 + i) * 2048);
            fa[i][1] = *(const bf16x8*)(sA + qo + (wr4 + i) * 2048 + 1024);
        }
    };
    auto READ_FB = [&](int qo) {
#pragma unroll
        for (int j = 0; j < 2; ++j) {
            fb[j][0] = *(const bf16x8*)(sB + qo + (wc2 + j) * 2048);
            fb[j][1] = *(const bf16x8*)(sB + qo + (wc2 + j) * 2048 + 1024);
        }
    };

    // prologue: K-step 0 (4 slots) + K-step 1 {Aq0,Bq0}; wait first 8 loads.
    STAGE_A(0, 0, 0); STAGE_B(0, 0, 0);
    STAGE_A(0, 1, 0); STAGE_B(0, 1, 0);
    STAGE_A(1, 0, 1); STAGE_B(1, 0, 1);
    asm volatile("s_waitcnt vmcnt(4)" ::: "memory");
    BAR();

#pragma unroll 1
    for (int it = 0; it < 24; ++it) {
        const int t1 = 2 * it + 1, t2 = t1 + 1, t3 = t1 + 2;

        // Ph1: K-step 2it, C(0,0)
        READ_FA(0);      READ_FB(0);
        STAGE_A(1, 1, t1);
        BAR();
        MFMA16(0, 0);
        BAR();
        // Ph2: C(0,1) — fa reused
        READ_FB(16384);
        STAGE_B(1, 1, t1);
        BAR();
        MFMA16(0, 1);
        BAR();
        // Ph3: C(1,0)
        READ_FA(16384);  READ_FB(0);
        STAGE_A(0, 0, t2);
        BAR();
        MFMA16(1, 0);
        BAR();
        // Ph4: C(1,1)
        READ_FB(16384);
        STAGE_B(0, 0, t2);
        if (it < 23) { asm volatile("s_waitcnt vmcnt(4)" ::: "memory"); }
        else         { asm volatile("s_waitcnt vmcnt(0)" ::: "memory"); }
        BAR();
        MFMA16(1, 1);
        BAR();
        // Ph5: K-step 2it+1, C(0,0)
        READ_FA(32768);  READ_FB(32768);
        STAGE_A(0, 1, t2);
        BAR();
        MFMA16(0, 0);
        BAR();
        // Ph6: C(0,1)
        READ_FB(49152);
        STAGE_B(0, 1, t2);
        BAR();
        MFMA16(0, 1);
        BAR();
        // Ph7: C(1,0)
        READ_FA(49152);  READ_FB(32768);
        STAGE_A(1, 0, t3);
        BAR();
        MFMA16(1, 0);
        BAR();
        // Ph8: C(1,1)
        READ_FB(49152);
        STAGE_B(1, 0, t3);
        asm volatile("s_waitcnt vmcnt(4)" ::: "memory");
        BAR();
        MFMA16(1, 1);
        BAR();
    }

    // epilogue: per-row argmax. C layout: col = lane&15, row = (lane>>4)*4+reg.
#pragma unroll
    for (int frq = 0; frq < 2; ++frq)
#pragma unroll
        for (int i = 0; i < 4; ++i)
#pragma unroll
            for (int r = 0; r < 4; ++r) {
                float bv = acc[frq][0][i][0][r];
                int   bn = wc * 32 + lcol;
                {   const float v = acc[frq][0][i][1][r];
                    if (v > bv) { bv = v; bn = wc * 32 + 16 + lcol; } }
                {   const float v = acc[frq][1][i][0][r];
                    if (v > bv) { bv = v; bn = 128 + wc * 32 + lcol; } }
                {   const float v = acc[frq][1][i][1][r];
                    if (v > bv) { bv = v; bn = 128 + wc * 32 + 16 + lcol; } }
                unsigned u = __float_as_uint(bv);
                u = (u & 0x80000000u) ? ~u : (u | 0x80000000u);
                u64 kkey = ((u64)u << 32)
                         | (u64)(0xFFFFFFFFu - (unsigned)(nt * 256 + bn));
#pragma unroll
                for (int sh = 1; sh < 16; sh <<= 1) {
                    const u64 o = __shfl_xor(kkey, sh, 64);
                    if (o > kkey) kkey = o;
                }
                if (lcol == 0) {
                    const int m = mt * 256 + frq * 128 + wr * 64 + i * 16 + lrow * 4 + r;
                    atomicMax(&assign_key[bb * M_ + m], kkey);
                }
            }
}

// ---------------------------------------------------------------------------
// Kernel 4 (fused count+scan+fill): unchanged.
// ---------------------------------------------------------------------------
__global__ __launch_bounds__(1024)
void binning_kernel(const u64* __restrict__ assign_key,
                    u32* __restrict__ offset, u32* __restrict__ list)
{
    const int b = blockIdx.x;
    const int t = threadIdx.x;
    __shared__ u32 cnt[1024];
    __shared__ u32 sb[1024];

    cnt[t] = 0u;
    __syncthreads();
    int kk[3];
#pragma unroll
    for (int i = 0; i < 3; ++i) {
        const int m = t + i * 1024;
        kk[i] = (int)(0xFFFFFFFFu - (unsigned)(assign_key[b * M_ + m] & 0xFFFFFFFFull));
        atomicAdd(&cnt[kk[i]], 1u);
    }
    __syncthreads();
    const u32 c = cnt[t];
    sb[t] = c;
    __syncthreads();
    for (int d = 1; d < 1024; d <<= 1) {
        const u32 v = (t >= d) ? sb[t - d] : 0u;
        __syncthreads();
        sb[t] += v;
        __syncthreads();
    }
    const u32 excl = sb[t] - c;
    offset[b * K_ + t] = excl;
    cnt[t] = excl;                      // reuse as cursor
    __syncthreads();
#pragma unroll
    for (int i = 0; i < 3; ++i) {
        const int m = t + i * 1024;
        const u32 pos = atomicAdd(&cnt[kk[i]], 1u);
        list[b * M_ + pos] = (u32)(b * M_ + m);
    }
}

// ---------------------------------------------------------------------------
// Kernel 5: gather-merge (unchanged).
// ---------------------------------------------------------------------------
__global__ __launch_bounds__(256)
void merge_kernel(const float* __restrict__ tokens, const float* __restrict__ scores,
                  const int* __restrict__ kept_idx, const float* __restrict__ kept_sc,
                  const int* __restrict__ dropped_idx,
                  const u32* __restrict__ offset, const u32* __restrict__ list,
                  float* __restrict__ out_tok)
{
    const int r = blockIdx.x;                   // [0, B*K)
    const int b = r >> 10;
    const int t = threadIdx.x;
    const u32 o = offset[r];
    const u32 e = ((r & (K_ - 1)) == K_ - 1) ? (u32)M_ : offset[r + 1];
    const float ksc = kept_sc[r];
    const int kIdx = kept_idx[r];

    float4 acc = *(const float4*)(tokens + ((size_t)b * N_ + kIdx) * D_ + t * 4);
    acc.x *= ksc; acc.y *= ksc; acc.z *= ksc; acc.w *= ksc;
    float ssum = 0.0f;

    for (u32 i = o; i < e; ++i) {
        const int g = (int)list[b * M_ + i];
        const int dIdx = dropped_idx[g];
        const float s = fmaxf(scores[b * N_ + dIdx], 0.0f);
        const float4 v = *(const float4*)(tokens + ((size_t)b * N_ + dIdx) * D_ + t * 4);
        acc.x += s * v.x; acc.y += s * v.y; acc.z += s * v.z; acc.w += s * v.w;
        ssum += s;
    }

    const float inv = 1.0f / fmaxf(ksc + ssum, 1e-6f);
    acc.x *= inv; acc.y *= inv; acc.z *= inv; acc.w *= inv;
    *(float4*)(out_tok + (size_t)r * D_ + t * 4) = acc;
}

// ---------------------------------------------------------------------------
extern "C" void kernel_launch(void* const* d_in, const int* in_sizes, int n_in,
                              void* d_out, int out_size, void* d_ws, size_t ws_size,
                              hipStream_t stream)
{
    const float* tokens = (const float*)d_in[0];
    const float* scores = (const float*)d_in[1];

    float* out = (float*)d_out;
    float* out_tok = out;                              // [B,K,D]
    float* out_idx = out + (size_t)B_ * K_ * D_;       // [B,K]
    float* out_sc  = out_idx + (size_t)B_ * K_;        // [B,K]

    char* ws = (char*)d_ws;
    int*   kept_idx    = (int*)(ws);                   //       0,  64 KB
    int*   dropped_idx = (int*)(ws + 65536);           //   64 KB, 192 KB
    float* kept_sc     = (float*)(ws + 262144);        //  256 KB,  64 KB
    u32*   rank        = (u32*)(ws + 327680);          //  320 KB, 256 KB
    u64*   assign_key  = (u64*)(ws + 589824);          //  576 KB, 384 KB
    u32*   offset      = (u32*)(ws + 983040);          //  960 KB,  64 KB
    u32*   list        = (u32*)(ws + 1048576);         // 1024 KB, 192 KB

    const size_t splitBase = 1310720;                  // 1.25 MB
    const size_t kSplit = (size_t)B_ * K_ * D_ * 2;    // 32 MB each
    const size_t dSplit = (size_t)B_ * M_ * D_ * 2;    // 96 MB each
    u16* khi = (u16*)(ws + splitBase);
    u16* klo = (u16*)((char*)khi + kSplit);
    u16* dhi = (u16*)((char*)klo + kSplit);
    u16* dlo = (u16*)((char*)dhi + dSplit);

    topk_kernel<<<B_, 1024, 0, stream>>>(scores, out_idx, out_sc,
                                         kept_idx, dropped_idx, kept_sc, rank,
                                         assign_key);

    convert_kernel<<<(B_ * N_) / 4, 256, 0, stream>>>(tokens, rank,
                                                      khi, klo, dhi, dlo);

    // 768 blocks = 16 b x 12 mt x 4 nt, 512 threads, 8-phase schedule
    sim_mfma_kernel<<<dim3(768), 512, 0, stream>>>(dhi, dlo, khi, klo, assign_key);

    binning_kernel<<<B_, 1024, 0, stream>>>(assign_key, offset, list);

    merge_kernel<<<B_ * K_, 256, 0, stream>>>(tokens, scores, kept_idx, kept_sc,
                                              dropped_idx, offset, list, out_tok);
}

// Round 2
// 772.550 us; speedup vs baseline: 1.1412x; 1.0011x over previous
//
#include <hip/hip_runtime.h>
#include <hip/hip_bf16.h>

#define B_ 16
#define N_ 4096
#define D_ 1024
#define K_ 1024
#define M_ 3072

typedef unsigned short u16;
typedef unsigned int u32;
typedef unsigned long long u64;
typedef __attribute__((ext_vector_type(8))) short bf16x8;
typedef __attribute__((ext_vector_type(4))) float f32x4;

// round-to-nearest-even fp32 -> bf16
__device__ inline u16 bf16_rn(float x) {
    unsigned u = __float_as_uint(x);
    u += 0x7fffu + ((u >> 16) & 1u);
    return (u16)(u >> 16);
}
__device__ inline void bf16_split(float x, u16& h, u16& l) {
    h = bf16_rn(x);
    const float hf = __uint_as_float(((unsigned)h) << 16);
    l = bf16_rn(x - hf);
}

// ---------------------------------------------------------------------------
// Kernel 1: per-batch top-K via u64 radix select (unchanged).
// ---------------------------------------------------------------------------
__global__ __launch_bounds__(1024)
void topk_kernel(const float* __restrict__ scores,
                 float* __restrict__ out_idx_f, float* __restrict__ out_sc,
                 int* __restrict__ kept_idx, int* __restrict__ dropped_idx,
                 float* __restrict__ kept_sc, u32* __restrict__ rank,
                 u64* __restrict__ assign_key)
{
    const int b = blockIdx.x;
    const int tid = threadIdx.x;
    __shared__ u32 hist[2048];
    __shared__ u32 wsum[16];
    __shared__ u64 s_thr;
    __shared__ u32 s_bb;

    for (int m = tid; m < M_; m += 1024) assign_key[b * M_ + m] = 0ull;

    float sval[4];
    u64 key[4];
#pragma unroll
    for (int r = 0; r < 4; ++r) {
        const int e = r * 1024 + tid;
        const float s = scores[b * N_ + e];
        sval[r] = s;
        unsigned sb = __float_as_uint(s);
        sb = (sb & 0x80000000u) ? ~sb : (sb | 0x80000000u);
        key[r] = ((u64)sb << 32) | (unsigned)(N_ - 1 - e);
    }

    u64 prefix = 0;
    u32 need = K_;
    int consumed = 0;
    bool done = false;

#pragma unroll
    for (int lvl = 0; lvl < 6; ++lvl) {
        if (!done) {
            const int w = (lvl < 5) ? 11 : 9;
            const int sh = 64 - consumed - w;

            hist[tid] = 0u; hist[tid + 1024] = 0u;
            __syncthreads();
#pragma unroll
            for (int r = 0; r < 4; ++r) {
                const bool cand = (lvl == 0) || ((key[r] >> (64 - consumed)) == prefix);
                if (cand) atomicAdd(&hist[(u32)(key[r] >> sh) & ((1u << w) - 1u)], 1u);
            }
            __syncthreads();
            for (int d = 1; d < 2048; d <<= 1) {
                const u32 v0 = (tid + d < 2048) ? hist[tid + d] : 0u;
                const u32 v1 = (tid + 1024 + d < 2048) ? hist[tid + 1024 + d] : 0u;
                __syncthreads();
                hist[tid] += v0; hist[tid + 1024] += v1;
                __syncthreads();
            }
#pragma unroll
            for (int h = 0; h < 2; ++h) {
                const int i = tid + h * 1024;
                if (hist[i] >= need && (i == 2047 || hist[i + 1] < need)) s_bb = (u32)i;
            }
            __syncthreads();
            const u32 bb = s_bb;
            const u32 c_hi = (bb < 2047u) ? hist[bb + 1] : 0u;
            const u32 cnt_bb = hist[bb] - c_hi;
            __syncthreads();

            prefix = (prefix << w) | bb;
            consumed += w;
            need -= c_hi;
            if (cnt_bb == need || consumed == 64) {
                if (tid == 0) s_thr = prefix << (64 - consumed);
                done = true;
            }
        }
    }
    __syncthreads();
    const u64 thr = s_thr;

    const int lane = tid & 63, wv = tid >> 6;
    unsigned carry = 0;
#pragma unroll
    for (int r = 0; r < 4; ++r) {
        const int e = r * 1024 + tid;
        const bool kept = (key[r] >= thr);

        const u64 mb = __ballot(kept);
        const unsigned lanePre = (unsigned)__popcll(mb & ((1ull << lane) - 1ull));
        if (lane == 0) wsum[wv] = (unsigned)__popcll(mb);
        __syncthreads();
        unsigned waveExcl = 0, roundTot = 0;
        for (int i = 0; i < 16; ++i) {
            const unsigned v = wsum[i];
            if (i < wv) waveExcl += v;
            roundTot += v;
        }
        const unsigned kpos = carry + waveExcl + lanePre;
        if (kept) {
            out_idx_f[b * K_ + kpos] = (float)e;
            out_sc  [b * K_ + kpos] = sval[r];
            kept_idx[b * K_ + kpos] = e;
            kept_sc [b * K_ + kpos] = fmaxf(sval[r], 0.0f);
            rank    [b * N_ + e]    = kpos;
        } else {
            const unsigned q = (unsigned)e - kpos;
            dropped_idx[b * M_ + q] = e;
            rank       [b * N_ + e] = (u32)K_ + q;
        }
        carry += roundTot;
        __syncthreads();
    }
}

// ---------------------------------------------------------------------------
// Kernel 2 (fused prep+conv): unchanged.
// ---------------------------------------------------------------------------
__global__ __launch_bounds__(256)
void convert_kernel(const float* __restrict__ tokens, const u32* __restrict__ rank,
                    u16* __restrict__ khi, u16* __restrict__ klo,
                    u16* __restrict__ dhi, u16* __restrict__ dlo)
{
    const int w = threadIdx.x >> 6, lane = threadIdx.x & 63;
    const int g = blockIdx.x * 4 + w;          // flat row in [0, B*N)
    const int b = g >> 12;                     // N_ = 4096
    const float* src = tokens + (size_t)g * D_;

    float4 v[4];
    float ss = 0.0f;
#pragma unroll
    for (int j = 0; j < 4; ++j) {
        v[j] = *(const float4*)(src + (lane + j * 64) * 4);
        ss += v[j].x * v[j].x + v[j].y * v[j].y + v[j].z * v[j].z + v[j].w * v[j].w;
    }
#pragma unroll
    for (int sh = 1; sh < 64; sh <<= 1) ss += __shfl_xor(ss, sh, 64);
    const float inv = 1.0f / fmaxf(sqrtf(ss), 1e-12f);

    const u32 r = rank[g];
    u16 *hp, *lp;
    if (r < (u32)K_) {
        hp = khi + ((size_t)b * K_ + r) * D_;
        lp = klo + ((size_t)b * K_ + r) * D_;
    } else {
        hp = dhi + ((size_t)b * M_ + (r - K_)) * D_;
        lp = dlo + ((size_t)b * M_ + (r - K_)) * D_;
    }
#pragma unroll
    for (int j = 0; j < 4; ++j) {
        ushort4 h, l;
        bf16_split(v[j].x * inv, h.x, l.x);
        bf16_split(v[j].y * inv, h.y, l.y);
        bf16_split(v[j].z * inv, h.z, l.z);
        bf16_split(v[j].w * inv, h.w, l.w);
        *(ushort4*)(hp + 4 * (lane + 64 * j)) = h;
        *(ushort4*)(lp + 4 * (lane + 64 * j)) = l;
    }
}

// ---------------------------------------------------------------------------
// Kernel 3 (MFMA, 8-phase counted-vmcnt, balanced (8,4,8,4) ds_read):
// sim = d_norm . k_norm^T as one GEMM over K = 3 x 1024 segments
// (seg0: dhi.khi, seg1: dlo.khi, seg2: dhi.klo).
// BM=BN=256, BK=64, 8 waves (2Mx4N), 512 thr, LDS 128 KiB, 8 slots x 16 KiB.
// Register B-reuse: fbq0/fbq1 hold both B column-halves for the K-step
// (48 ds_read_b128/iter vs 64 before); fbq0 is read one phase ahead (Ph4
// reads next K-step's, Ph8 reads K-step t+2's from the parity-0 slot).
// Phase p: {ds_read (8 or 4), stage 1 slot, [vmcnt @Ph4/8], bar, MFMA, bar}.
// Stage rotation = one phase after each slot's last read:
//  Ph1:Bq0P0<-t+2 Ph2:Aq0P0<-t+2 Ph3:Bq1P0<-t+2 Ph4:Aq1P0<-t+2
//  Ph5:Bq0P1<-t+3 Ph6:Aq0P1<-t+3 Ph7:Bq1P1<-t+3 Ph8:Aq1P1<-t+3
// vmcnt(4) at Ph4 completes loads through Ph2 (covers Ph5-8 reads);
// at Ph8 completes through Ph6 (covers next Ph1-4). Last iter: vmcnt(0)
// at Ph4 (its own stages are all skipped, must drain iter-22 Ph7/Ph8).
// Fused row-argmax epilogue via packed u64 atomicMax (max sim, tie->min n).
// ---------------------------------------------------------------------------
#define BAR() asm volatile("s_barrier" ::: "memory")

#define MFMA16(FRQ, FCQ, FB) do {                                           \
    __builtin_amdgcn_s_setprio(1);                                          \
    _Pragma("unroll") for (int i_ = 0; i_ < 4; ++i_)                        \
    _Pragma("unroll") for (int j_ = 0; j_ < 2; ++j_) {                      \
        acc[FRQ][FCQ][i_][j_] = __builtin_amdgcn_mfma_f32_16x16x32_bf16(    \
            fa[i_][0], FB[j_][0], acc[FRQ][FCQ][i_][j_], 0, 0, 0);          \
        acc[FRQ][FCQ][i_][j_] = __builtin_amdgcn_mfma_f32_16x16x32_bf16(    \
            fa[i_][1], FB[j_][1], acc[FRQ][FCQ][i_][j_], 0, 0, 0);          \
    }                                                                       \
    __builtin_amdgcn_s_setprio(0);                                          \
} while (0)

__global__ __launch_bounds__(512, 2)
void sim_mfma_kernel(const u16* __restrict__ dhi, const u16* __restrict__ dlo,
                     const u16* __restrict__ khi, const u16* __restrict__ klo,
                     u64* __restrict__ assign_key)
{
    // XCD-aware swizzle: 768 blocks = 8 XCD x 96; within an XCD, 12
    // consecutive blocks share nt (kept panel) for L2 reuse.
    const int gid = blockIdx.x;
    const int vid = (gid & 7) * 96 + (gid >> 3);
    const int bb  = vid / 48;
    const int tt  = vid - bb * 48;
    const int nt  = tt / 12;                   // [0,4)  kept tile (256)
    const int mt  = tt - nt * 12;              // [0,12) dropped tile (256)

    const int tid = threadIdx.x;
    const int w = tid >> 6, lane = tid & 63;
    const int wr = w >> 2, wc = w & 3;         // wave grid 2(M) x 4(N)
    const int wr4 = wr * 4, wc2 = wc * 2;
    const int lrow = lane >> 4, lcol = lane & 15;

    __shared__ __align__(16) char smem[131072];
    const char* sA = smem + lane * 16;
    const char* sB = smem + 65536 + lane * 16;

    // per-lane global row offsets (wave w stages fragment-row w of a slot)
    const size_t aOff = ((size_t)bb * M_ + mt * 256 + w * 16 + lcol) * D_ + lrow * 8;
    const size_t bOff = ((size_t)bb * K_ + nt * 256 + w * 16 + lcol) * D_ + lrow * 8;

    f32x4 acc[2][2][4][2];                     // [frq][fcq][i][j]
#pragma unroll
    for (int a0 = 0; a0 < 2; ++a0)
#pragma unroll
        for (int a1 = 0; a1 < 2; ++a1)
#pragma unroll
            for (int a2 = 0; a2 < 4; ++a2)
#pragma unroll
                for (int a3 = 0; a3 < 2; ++a3)
                    acc[a0][a1][a2][a3] = (f32x4){0.f, 0.f, 0.f, 0.f};

    bf16x8 fa[4][2];           // A frags for current frq half (32 VGPR)
    bf16x8 fbq0[2][2];         // B frags, column-half q0 (16 VGPR)
    bf16x8 fbq1[2][2];         // B frags, column-half q1 (16 VGPR)

    // A slot (q,P): byte off (P*2+q)*16384; B same + 65536.
    auto STAGE_A = [&](int P, int q, int t) {
        if (t < 48) {
            const u16* s = ((t >> 4) == 1) ? dlo : dhi;     // seg 0,2: hi; 1: lo
            const u16* gp = s + aOff + (size_t)(q * 131072) + ((t & 15) * 64);
            char* lp = smem + (P * 2 + q) * 16384 + w * 2048;
            __builtin_amdgcn_global_load_lds(
                (const __attribute__((address_space(1))) void*)gp,
                (__attribute__((address_space(3))) void*)lp, 16, 0, 0);
            __builtin_amdgcn_global_load_lds(
                (const __attribute__((address_space(1))) void*)(gp + 32),
                (__attribute__((address_space(3))) void*)(lp + 1024), 16, 0, 0);
        }
    };
    auto STAGE_B = [&](int P, int q, int t) {
        if (t < 48) {
            const u16* s = ((t >> 4) == 2) ? klo : khi;     // seg 0,1: hi; 2: lo
            const u16* gp = s + bOff + (size_t)(q * 131072) + ((t & 15) * 64);
            char* lp = smem + 65536 + (P * 2 + q) * 16384 + w * 2048;
            __builtin_amdgcn_global_load_lds(
                (const __attribute__((address_space(1))) void*)gp,
                (__attribute__((address_space(3))) void*)lp, 16, 0, 0);
            __builtin_amdgcn_global_load_lds(
                (const __attribute__((address_space(1))) void*)(gp + 32),
                (__attribute__((address_space(3))) void*)(lp + 1024), 16, 0, 0);
        }
    };
    auto READ_FA = [&](int qo) {               // 8 x ds_read_b128
#pragma unroll
        for (int i = 0; i < 4; ++i) {
            fa[i][0] = *(const bf16x8*)(sA + qo + (wr4 + i) * 2048);
            fa[i][1] = *(const bf16x8*)(sA + qo + (wr4 + i) * 2048 + 1024);
        }
    };
    auto READ_FB = [&](int qo, bf16x8 (*fb)[2]) {   // 4 x ds_read_b128
#pragma unroll
        for (int j = 0; j < 2; ++j) {
            fb[j][0] = *(const bf16x8*)(sB + qo + (wc2 + j) * 2048);
            fb[j][1] = *(const bf16x8*)(sB + qo + (wc2 + j) * 2048 + 1024);
        }
    };

    // prologue: stage all 8 slots (K-steps 0 and 1), drain, pre-read fbq0[0].
    STAGE_B(0, 0, 0); STAGE_A(0, 0, 0);
    STAGE_B(0, 1, 0); STAGE_A(0, 1, 0);
    STAGE_B(1, 0, 1); STAGE_A(1, 0, 1);
    STAGE_B(1, 1, 1); STAGE_A(1, 1, 1);
    asm volatile("s_waitcnt vmcnt(0)" ::: "memory");
    BAR();
    READ_FB(0, fbq0);                          // fbq0 <- K-step 0 (slot Bq0P0)
    BAR();

#pragma unroll 1
    for (int it = 0; it < 24; ++it) {
        const int t2 = 2 * it + 2, t3 = 2 * it + 3;

        // ---- K-step 2it (parity 0) ----
        // Ph1: C(0,0)   fa<-Aq0P0, fbq0 pre-read
        READ_FA(0);
        STAGE_B(0, 0, t2);
        BAR();
        MFMA16(0, 0, fbq0);
        BAR();
        // Ph2: C(0,1)   fbq1<-Bq1P0
        READ_FB(16384, fbq1);
        STAGE_A(0, 0, t2);
        BAR();
        MFMA16(0, 1, fbq1);
        BAR();
        // Ph3: C(1,0)   fa<-Aq1P0, fbq0 reused
        READ_FA(16384);
        STAGE_B(0, 1, t2);
        BAR();
        MFMA16(1, 0, fbq0);
        BAR();
        // Ph4: C(1,1)   fbq0<-Bq0P1 (next K-step), fbq1 reused
        READ_FB(32768, fbq0);
        STAGE_A(0, 1, t2);
        if (it < 23) { asm volatile("s_waitcnt vmcnt(4)" ::: "memory"); }
        else         { asm volatile("s_waitcnt vmcnt(0)" ::: "memory"); }
        BAR();
        MFMA16(1, 1, fbq1);
        BAR();

        // ---- K-step 2it+1 (parity 1) ----
        // Ph5: C(0,0)   fa<-Aq0P1
        READ_FA(32768);
        STAGE_B(1, 0, t3);
        BAR();
        MFMA16(0, 0, fbq0);
        BAR();
        // Ph6: C(0,1)   fbq1<-Bq1P1
        READ_FB(49152, fbq1);
        STAGE_A(1, 0, t3);
        BAR();
        MFMA16(0, 1, fbq1);
        BAR();
        // Ph7: C(1,0)   fa<-Aq1P1
        READ_FA(49152);
        STAGE_B(1, 1, t3);
        BAR();
        MFMA16(1, 0, fbq0);
        BAR();
        // Ph8: C(1,1)   fbq0<-Bq0P0 (K-step t+2; stale garbage on last iter,
        //               never consumed)
        READ_FB(0, fbq0);
        STAGE_A(1, 1, t3);
        asm volatile("s_waitcnt vmcnt(4)" ::: "memory");
        BAR();
        MFMA16(1, 1, fbq1);
        BAR();
    }

    // epilogue: per-row argmax. C layout: col = lane&15, row = (lane>>4)*4+reg.
#pragma unroll
    for (int frq = 0; frq < 2; ++frq)
#pragma unroll
        for (int i = 0; i < 4; ++i)
#pragma unroll
            for (int r = 0; r < 4; ++r) {
                float bv = acc[frq][0][i][0][r];
                int   bn = wc * 32 + lcol;
                {   const float v = acc[frq][0][i][1][r];
                    if (v > bv) { bv = v; bn = wc * 32 + 16 + lcol; } }
                {   const float v = acc[frq][1][i][0][r];
                    if (v > bv) { bv = v; bn = 128 + wc * 32 + lcol; } }
                {   const float v = acc[frq][1][i][1][r];
                    if (v > bv) { bv = v; bn = 128 + wc * 32 + 16 + lcol; } }
                unsigned u = __float_as_uint(bv);
                u = (u & 0x80000000u) ? ~u : (u | 0x80000000u);
                u64 kkey = ((u64)u << 32)
                         | (u64)(0xFFFFFFFFu - (unsigned)(nt * 256 + bn));
#pragma unroll
                for (int sh = 1; sh < 16; sh <<= 1) {
                    const u64 o = __shfl_xor(kkey, sh, 64);
                    if (o > kkey) kkey = o;
                }
                if (lcol == 0) {
                    const int m = mt * 256 + frq * 128 + wr * 64 + i * 16 + lrow * 4 + r;
                    atomicMax(&assign_key[bb * M_ + m], kkey);
                }
            }
}

// ---------------------------------------------------------------------------
// Kernel 4 (fused count+scan+fill): unchanged.
// ---------------------------------------------------------------------------
__global__ __launch_bounds__(1024)
void binning_kernel(const u64* __restrict__ assign_key,
                    u32* __restrict__ offset, u32* __restrict__ list)
{
    const int b = blockIdx.x;
    const int t = threadIdx.x;
    __shared__ u32 cnt[1024];
    __shared__ u32 sb[1024];

    cnt[t] = 0u;
    __syncthreads();
    int kk[3];
#pragma unroll
    for (int i = 0; i < 3; ++i) {
        const int m = t + i * 1024;
        kk[i] = (int)(0xFFFFFFFFu - (unsigned)(assign_key[b * M_ + m] & 0xFFFFFFFFull));
        atomicAdd(&cnt[kk[i]], 1u);
    }
    __syncthreads();
    const u32 c = cnt[t];
    sb[t] = c;
    __syncthreads();
    for (int d = 1; d < 1024; d <<= 1) {
        const u32 v = (t >= d) ? sb[t - d] : 0u;
        __syncthreads();
        sb[t] += v;
        __syncthreads();
    }
    const u32 excl = sb[t] - c;
    offset[b * K_ + t] = excl;
    cnt[t] = excl;                      // reuse as cursor
    __syncthreads();
#pragma unroll
    for (int i = 0; i < 3; ++i) {
        const int m = t + i * 1024;
        const u32 pos = atomicAdd(&cnt[kk[i]], 1u);
        list[b * M_ + pos] = (u32)(b * M_ + m);
    }
}

// ---------------------------------------------------------------------------
// Kernel 5: gather-merge (unchanged).
// ---------------------------------------------------------------------------
__global__ __launch_bounds__(256)
void merge_kernel(const float* __restrict__ tokens, const float* __restrict__ scores,
                  const int* __restrict__ kept_idx, const float* __restrict__ kept_sc,
                  const int* __restrict__ dropped_idx,
                  const u32* __restrict__ offset, const u32* __restrict__ list,
                  float* __restrict__ out_tok)
{
    const int r = blockIdx.x;                   // [0, B*K)
    const int b = r >> 10;
    const int t = threadIdx.x;
    const u32 o = offset[r];
    const u32 e = ((r & (K_ - 1)) == K_ - 1) ? (u32)M_ : offset[r + 1];
    const float ksc = kept_sc[r];
    const int kIdx = kept_idx[r];

    float4 acc = *(const float4*)(tokens + ((size_t)b * N_ + kIdx) * D_ + t * 4);
    acc.x *= ksc; acc.y *= ksc; acc.z *= ksc; acc.w *= ksc;
    float ssum = 0.0f;

    for (u32 i = o; i < e; ++i) {
        const int g = (int)list[b * M_ + i];
        const int dIdx = dropped_idx[g];
        const float s = fmaxf(scores[b * N_ + dIdx], 0.0f);
        const float4 v = *(const float4*)(tokens + ((size_t)b * N_ + dIdx) * D_ + t * 4);
        acc.x += s * v.x; acc.y += s * v.y; acc.z += s * v.z; acc.w += s * v.w;
        ssum += s;
    }

    const float inv = 1.0f / fmaxf(ksc + ssum, 1e-6f);
    acc.x *= inv; acc.y *= inv; acc.z *= inv; acc.w *= inv;
    *(float4*)(out_tok + (size_t)r * D_ + t * 4) = acc;
}

// ---------------------------------------------------------------------------
extern "C" void kernel_launch(void* const* d_in, const int* in_sizes, int n_in,
                              void* d_out, int out_size, void* d_ws, size_t ws_size,
                              hipStream_t stream)
{
    const float* tokens = (const float*)d_in[0];
    const float* scores = (const float*)d_in[1];

    float* out = (float*)d_out;
    float* out_tok = out;                              // [B,K,D]
    float* out_idx = out + (size_t)B_ * K_ * D_;       // [B,K]
    float* out_sc  = out_idx + (size_t)B_ * K_;        // [B,K]

    char* ws = (char*)d_ws;
    int*   kept_idx    = (int*)(ws);                   //       0,  64 KB
    int*   dropped_idx = (int*)(ws + 65536);           //   64 KB, 192 KB
    float* kept_sc     = (float*)(ws + 262144);        //  256 KB,  64 KB
    u32*   rank        = (u32*)(ws + 327680);          //  320 KB, 256 KB
    u64*   assign_key  = (u64*)(ws + 589824);          //  576 KB, 384 KB
    u32*   offset      = (u32*)(ws + 983040);          //  960 KB,  64 KB
    u32*   list        = (u32*)(ws + 1048576);         // 1024 KB, 192 KB

    const size_t splitBase = 1310720;                  // 1.25 MB
    const size_t kSplit = (size_t)B_ * K_ * D_ * 2;    // 32 MB each
    const size_t dSplit = (size_t)B_ * M_ * D_ * 2;    // 96 MB each
    u16* khi = (u16*)(ws + splitBase);
    u16* klo = (u16*)((char*)khi + kSplit);
    u16* dhi = (u16*)((char*)klo + kSplit);
    u16* dlo = (u16*)((char*)dhi + dSplit);

    topk_kernel<<<B_, 1024, 0, stream>>>(scores, out_idx, out_sc,
                                         kept_idx, dropped_idx, kept_sc, rank,
                                         assign_key);

    convert_kernel<<<(B_ * N_) / 4, 256, 0, stream>>>(tokens, rank,
                                                      khi, klo, dhi, dlo);

    // 768 blocks = 16 b x 12 mt x 4 nt, 512 threads, 8-phase schedule
    sim_mfma_kernel<<<dim3(768), 512, 0, stream>>>(dhi, dlo, khi, klo, assign_key);

    binning_kernel<<<B_, 1024, 0, stream>>>(assign_key, offset, list);

    merge_kernel<<<B_ * K_, 256, 0, stream>>>(tokens, scores, kept_idx, kept_sc,
                                              dropped_idx, offset, list, out_tok);
}